// Round 15
// baseline (36.482 us; speedup 1.0000x reference)
//
#include <hip/hip_runtime.h>
#include <hip/hip_bf16.h>

// InferenceLinear: out[m][n] = sum_k x[m][k] * (q[n][k]*qrange[n][k/256] + qmin[n][k/256])
// M=512, N=2048, K=4096, 16 groups of 256.
// R15: LDS-read-bound fix. GEMM reshaped to 4 waves (2x2) of 64x64 wave tiles
// (256 thr, BM=BN=128): 8 ds_read_b128 per 16 MFMA = 3.8KB/MFLOP (was 5.7),
// 4 blocks/CU (4 independent barrier domains, 128KB LDS exactly). Staging keeps
// inverse-swizzled global_load_lds (linear dest = base + lane*16).
// Pipeline unchanged: pack -> gemm (KSPLIT=8, ws fp32 partials) -> reduce.

#define M_T 512
#define N_T 2048
#define K_T 4096
#define NGRP 16
#define BM 128
#define BN 128
#define BK 64
#define OUT_ELEMS (M_T * N_T)
#define W_ELEMS (N_T * K_T)          // 8388608 bf16
#define X_ELEMS (M_T * K_T)          // 2097152 bf16

typedef __attribute__((ext_vector_type(8))) short mfrag_t;           // 8 bf16 (4 VGPR)
typedef __attribute__((ext_vector_type(8))) unsigned short u16x8;
typedef __attribute__((ext_vector_type(4))) float f32x4;

__device__ __forceinline__ unsigned short f2bf(float f) {
  union { __hip_bfloat16 h; unsigned short u; } c;
  c.h = __float2bfloat16(f);
  return c.u;
}

// ---- pass 1: dequant W (int32 q -> bf16) + cast X (fp32 -> bf16) ----
__global__ __launch_bounds__(256) void pack_kernel(
    const float* __restrict__ x, const int* __restrict__ qw,
    const float* __restrict__ qrange, const float* __restrict__ qmin,
    unsigned short* __restrict__ wsW, unsigned short* __restrict__ wsX) {
  const int bid = blockIdx.x;
  const int tid = threadIdx.x;
  if (bid < (W_ELEMS / 8) / 256) {
    const int gidx = bid * 256 + tid;        // [0, 1048576)
    const int o = gidx >> 9;                 // 512 groups-of-8 per row
    const int k8 = gidx & 511;
    const int g = k8 >> 5;                   // 32 groups-of-8 per quant group
    const float sc = qrange[o * NGRP + g];
    const float mn = qmin[o * NGRP + g];
    const int4* q = (const int4*)(qw + ((size_t)o << 12) + (k8 << 3));
    const int4 q0 = q[0], q1 = q[1];
    u16x8 p;
    p[0] = f2bf((float)q0.x * sc + mn); p[1] = f2bf((float)q0.y * sc + mn);
    p[2] = f2bf((float)q0.z * sc + mn); p[3] = f2bf((float)q0.w * sc + mn);
    p[4] = f2bf((float)q1.x * sc + mn); p[5] = f2bf((float)q1.y * sc + mn);
    p[6] = f2bf((float)q1.z * sc + mn); p[7] = f2bf((float)q1.w * sc + mn);
    *(u16x8*)(wsW + ((size_t)gidx << 3)) = p;
  } else {
    const int gidx = (bid - (W_ELEMS / 8) / 256) * 256 + tid;  // [0, 262144)
    const float4* a = (const float4*)(x + ((size_t)gidx << 3));
    const float4 a0 = a[0], a1 = a[1];
    u16x8 p;
    p[0] = f2bf(a0.x); p[1] = f2bf(a0.y); p[2] = f2bf(a0.z); p[3] = f2bf(a0.w);
    p[4] = f2bf(a1.x); p[5] = f2bf(a1.y); p[6] = f2bf(a1.z); p[7] = f2bf(a1.w);
    *(u16x8*)(wsX + ((size_t)gidx << 3)) = p;
  }
}

// ---- pass 2: bf16 GEMM, 4 waves of 64x64, global_load_lds staging ----
template <int KSPLIT, bool XCDSWZ>
__global__ __launch_bounds__(256, 4) void dq_gemm_kernel(
    const unsigned short* __restrict__ wsX, const unsigned short* __restrict__ wsW,
    float* __restrict__ dst) {
  constexpr int KC = K_T / KSPLIT;
  constexpr int NTC = KC / BK;

  // physical layout: [row][slot^(row&7)], slot = 8-elem (16B) unit; linear fill
  __shared__ __align__(16) unsigned short As[BM * BK];
  __shared__ __align__(16) unsigned short Bs[BN * BK];

  const int tid = threadIdx.x;
  int xt, yt, kc;
  if (XCDSWZ) {
    const int b = blockIdx.x;
    kc = b & 7;                 // XCD id == k-chunk (assumes b%8 round-robin)
    const int slot = b >> 3;
    xt = slot & 15;             // n-tile
    yt = slot >> 4;             // m-tile
  } else {
    const int b = blockIdx.x;
    xt = b & 15;
    yt = (b >> 4) & 3;
    kc = b >> 6;
  }
  const int n0 = xt * BN;
  const int m0 = yt * BM;
  const int kbase = kc * KC;

  const int lane = tid & 63;
  const int wv = tid >> 6;           // 0..3

  // ---- staging mapping: wave wv covers rows [wv*32, wv*32+32) in 4 chunks of
  // 8 rows. lane l -> row += (l>>3), phys slot = l&7. LDS[row][p] holds logical
  // data[p ^ (row&7)]; row&7 == l>>3, so global source col16 = (l&7)^(l>>3).
  // gload_lds dest is linear: base + lane*16B == row*128B + slot*16B. ----
  const int srow8 = lane >> 3;       // 0..7
  const int scol = (((lane & 7) ^ srow8) << 3);   // elem offset
  const unsigned short* gA = wsX + (size_t)(m0 + wv * 32 + srow8) * K_T + kbase + scol;
  const unsigned short* gB = wsW + (size_t)(n0 + wv * 32 + srow8) * K_T + kbase + scol;
  unsigned short* lA = &As[wv * 32 * BK];   // 4KB per wave chunk-base
  unsigned short* lB = &Bs[wv * 32 * BK];

#define STAGE(T)                                                              \
  do {                                                                        \
    const size_t o_ = (size_t)(T) * BK;                                       \
    _Pragma("unroll")                                                         \
    for (int c_ = 0; c_ < 4; ++c_) {                                          \
      __builtin_amdgcn_global_load_lds(                                       \
          (const __attribute__((address_space(1))) void*)(gA + o_ + (size_t)c_ * 8 * K_T), \
          (__attribute__((address_space(3))) void*)(lA + c_ * 8 * BK), 16, 0, 0); \
      __builtin_amdgcn_global_load_lds(                                       \
          (const __attribute__((address_space(1))) void*)(gB + o_ + (size_t)c_ * 8 * K_T), \
          (__attribute__((address_space(3))) void*)(lB + c_ * 8 * BK), 16, 0, 0); \
    }                                                                         \
  } while (0)

  // ---- compute mapping: 4 waves 2(M) x 2(N); wave tile 64x64 (4x4 frags) ----
  const int wm = (wv >> 1) * 64;     // 0,64
  const int wn = (wv & 1) * 64;      // 0,64
  const int lr = lane & 15;
  const int lq = lane >> 4;
  const int rxl = lr & 7;            // read-side xor (row&7 == lr&7)

  f32x4 acc[4][4] = {};

  for (int t = 0; t < NTC; ++t) {
    if (t > 0) __syncthreads();      // all waves done reading before overwrite
    STAGE(t);
    __syncthreads();                 // drains vmcnt(0): tile visible

#pragma unroll
    for (int kk = 0; kk < 2; ++kk) {
      const int so = ((kk * 4 + lq) ^ rxl) << 3;
      mfrag_t bf[4];
#pragma unroll
      for (int fn = 0; fn < 4; ++fn)
        bf[fn] = *(const mfrag_t*)&Bs[(wn + fn * 16 + lr) * BK + so];
#pragma unroll
      for (int fm = 0; fm < 4; ++fm) {
        mfrag_t af = *(const mfrag_t*)&As[(wm + fm * 16 + lr) * BK + so];
#pragma unroll
        for (int fn = 0; fn < 4; ++fn)
          acc[fm][fn] = __builtin_amdgcn_mfma_f32_16x16x32_bf16(af, bf[fn], acc[fm][fn], 0, 0, 0);
      }
    }
  }
#undef STAGE

  // ---- epilogue: plain stores of partials to ws slice ----
  // C/D layout col=lane&15, row=(lane>>4)*4+reg (measured m89/m91)
  float* base = dst + (size_t)kc * OUT_ELEMS;
#pragma unroll
  for (int fm = 0; fm < 4; ++fm) {
#pragma unroll
    for (int fn = 0; fn < 4; ++fn) {
      const int rr = m0 + wm + fm * 16 + lq * 4;
      const int c = n0 + wn + fn * 16 + lr;
      float* op = base + (size_t)rr * N_T + c;
      op[0 * (size_t)N_T] = acc[fm][fn][0];
      op[1 * (size_t)N_T] = acc[fm][fn][1];
      op[2 * (size_t)N_T] = acc[fm][fn][2];
      op[3 * (size_t)N_T] = acc[fm][fn][3];
    }
  }
}

// ---- pass 3: out[i] = sum_s partials[s][i], deterministic order ----
template <int KSPLIT>
__global__ __launch_bounds__(256) void reduce_kernel(const float* __restrict__ ws,
                                                     float* __restrict__ out) {
  const int i4 = blockIdx.x * 256 + threadIdx.x;
  const size_t base = (size_t)i4 * 4;
  float4 a = *(const float4*)(ws + base);
#pragma unroll
  for (int s = 1; s < KSPLIT; ++s) {
    float4 b = *(const float4*)(ws + (size_t)s * OUT_ELEMS + base);
    a.x += b.x; a.y += b.y; a.z += b.z; a.w += b.w;
  }
  *(float4*)(out + base) = a;
}

// ---- fallback only (never expected to run): naive dot per output elem ----
__global__ void naive_kernel(const float* __restrict__ x, const int* __restrict__ qw,
                             const float* __restrict__ qrange, const float* __restrict__ qmin,
                             float* __restrict__ out) {
  const int idx = blockIdx.x * 256 + threadIdx.x;
  if (idx >= OUT_ELEMS) return;
  const int m = idx / N_T, n = idx % N_T;
  float s = 0.f;
  for (int g = 0; g < NGRP; ++g) {
    const float sc = qrange[n * NGRP + g], mn = qmin[n * NGRP + g];
    float d = 0.f, xs = 0.f;
    for (int k = g * 256; k < (g + 1) * 256; ++k) {
      d += x[(size_t)m * K_T + k] * (float)qw[(size_t)n * K_T + k];
      xs += x[(size_t)m * K_T + k];
    }
    s += d * sc + xs * mn;
  }
  out[idx] = s;
}

extern "C" void kernel_launch(void* const* d_in, const int* in_sizes, int n_in,
                              void* d_out, int out_size, void* d_ws, size_t ws_size,
                              hipStream_t stream) {
  const float* x = (const float*)d_in[0];
  const int* qw = (const int*)d_in[1];
  const float* qr = (const float*)d_in[2];
  const float* qm = (const float*)d_in[3];
  float* out = (float*)d_out;

  constexpr int KS = 8;
  unsigned short* wsW = (unsigned short*)d_ws;
  unsigned short* wsX = wsW + W_ELEMS;
  float* partials = (float*)(wsX + X_ELEMS);
  const size_t need = (size_t)W_ELEMS * 2 + (size_t)X_ELEMS * 2 +
                      (size_t)KS * OUT_ELEMS * sizeof(float);
  if (ws_size >= need) {
    const int packblk = (W_ELEMS / 8) / 256 + (X_ELEMS / 8) / 256;  // 4096+1024
    pack_kernel<<<packblk, 256, 0, stream>>>(x, qw, qr, qm, wsW, wsX);
    const int nblk = (N_T / BN) * (M_T / BM) * KS;  // 512
    dq_gemm_kernel<KS, true><<<nblk, dim3(256, 1, 1), 0, stream>>>(wsX, wsW, partials);
    reduce_kernel<KS><<<OUT_ELEMS / 4 / 256, 256, 0, stream>>>(partials, out);
  } else {
    naive_kernel<<<(OUT_ELEMS + 255) / 256, 256, 0, stream>>>(x, qw, qr, qm, out);
  }
}